// Round 2
// baseline (308.229 us; speedup 1.0000x reference)
//
#include <hip/hip_runtime.h>

#define B_ROWS   16384
#define D_DIM    2048
#define L_LAYERS 6
#define THREADS  512                      // 8 waves/block
#define BLOCKS   1024                     // 8192 waves, 2 rows per wave
#define WPB      (THREADS / 64)
#define ROWS_PER_WAVE 2

// Identity used (exact algebra, handles arbitrary b):
//   x_l = c_l * x0 + u_l,  u_l = sum_{i<l} b_i (const vector),
//   c_{l+1} = c_l*(1 + x0.W_l) + u_l.W_l,  c_0 = 1, u_0 = 0.
// => whole net = 6 dots per row + scalar recurrence + out = c*x0 + U.
//
// Structure: W,U staged in LDS once per block (ONE barrier total), then each
// wave owns full rows (lane holds 32 x-values), butterfly-reduces in-wave —
// zero barriers in the row phase, 16 float4 loads in flight per lane.
__global__ __launch_bounds__(THREADS, 4) void cross_net_kernel(
    const float* __restrict__ x,
    const float* __restrict__ W,
    const float* __restrict__ b,
    float* __restrict__ out)
{
    __shared__ float Wl[L_LAYERS][D_DIM];   // 48 KB
    __shared__ float Ul[D_DIM];             // 8 KB
    __shared__ float red[WPB][L_LAYERS];    // setup reduction scratch

    const int t    = threadIdx.x;
    const int lane = t & 63;
    const int wid  = t >> 6;

    // ---------------- setup: stage W, compute U = sum b_i, e[l] = (sum_{i<l} b_i).W_l
    {
        const int base = t * 4;             // 512 threads x 4 = 2048
        float4 prefix = make_float4(0.f, 0.f, 0.f, 0.f);
        float e_red[L_LAYERS];
        #pragma unroll
        for (int l = 0; l < L_LAYERS; ++l) {
            const float4 wv = *(const float4*)(W + l * D_DIM + base);
            const float4 bv = *(const float4*)(b + l * D_DIM + base);
            e_red[l] = prefix.x * wv.x + prefix.y * wv.y +
                       prefix.z * wv.z + prefix.w * wv.w;   // prefix BEFORE b_l
            prefix.x += bv.x; prefix.y += bv.y; prefix.z += bv.z; prefix.w += bv.w;
            *(float4*)&Wl[l][base] = wv;
        }
        *(float4*)&Ul[base] = prefix;
        #pragma unroll
        for (int l = 0; l < L_LAYERS; ++l) {
            float v = e_red[l];
            #pragma unroll
            for (int off = 32; off >= 1; off >>= 1) v += __shfl_xor(v, off, 64);
            if (lane == 0) red[wid][l] = v;
        }
    }
    __syncthreads();                        // the ONLY barrier

    float e[L_LAYERS];
    #pragma unroll
    for (int l = 0; l < L_LAYERS; ++l) {
        float s = 0.f;
        #pragma unroll
        for (int w = 0; w < WPB; ++w) s += red[w][l];  // wave-uniform broadcast reads
        e[l] = s;
    }

    // ---------------- row phase: barrier-free, one wave per row-pair
    const int gw   = blockIdx.x * WPB + wid;         // global wave id, 0..8191
    const int row0 = gw * ROWS_PER_WAVE;
    const float* xr0 = x + (size_t)row0 * D_DIM;
    const float* xr1 = xr0 + D_DIM;
    const int eoff = lane * 4;                       // + j*256, j=0..7 covers 2048

    // prefetch both rows: 16 coalesced float4 loads in flight
    float4 xa[8], xb[8];
    #pragma unroll
    for (int j = 0; j < 8; ++j) xa[j] = *(const float4*)(xr0 + j * 256 + eoff);
    #pragma unroll
    for (int j = 0; j < 8; ++j) xb[j] = *(const float4*)(xr1 + j * 256 + eoff);

    // 12 partial dots; each W fragment read once from LDS, used for both rows
    float p0[L_LAYERS], p1[L_LAYERS];
    #pragma unroll
    for (int l = 0; l < L_LAYERS; ++l) {
        float a0 = 0.f, a1 = 0.f;
        #pragma unroll
        for (int j = 0; j < 8; ++j) {
            const float4 wv = *(const float4*)&Wl[l][j * 256 + eoff];
            a0 += xa[j].x * wv.x + xa[j].y * wv.y + xa[j].z * wv.z + xa[j].w * wv.w;
            a1 += xb[j].x * wv.x + xb[j].y * wv.y + xb[j].z * wv.z + xb[j].w * wv.w;
        }
        p0[l] = a0; p1[l] = a1;
    }

    // in-wave butterfly reduce — 12 independent chains, no LDS round-trip
    #pragma unroll
    for (int off = 32; off >= 1; off >>= 1) {
        #pragma unroll
        for (int l = 0; l < L_LAYERS; ++l) {
            p0[l] += __shfl_xor(p0[l], off, 64);
            p1[l] += __shfl_xor(p1[l], off, 64);
        }
    }

    // scalar recurrence (uniform across lanes after full reduce)
    float c0 = 1.f, c1 = 1.f;
    #pragma unroll
    for (int l = 0; l < L_LAYERS; ++l) {
        c0 = c0 * (1.f + p0[l]) + e[l];
        c1 = c1 * (1.f + p1[l]) + e[l];
    }

    // out = c * x0 + U
    float* or0 = out + (size_t)row0 * D_DIM;
    float* or1 = or0 + D_DIM;
    #pragma unroll
    for (int j = 0; j < 8; ++j) {
        const float4 uv = *(const float4*)&Ul[j * 256 + eoff];
        float4 o0, o1;
        o0.x = c0 * xa[j].x + uv.x; o0.y = c0 * xa[j].y + uv.y;
        o0.z = c0 * xa[j].z + uv.z; o0.w = c0 * xa[j].w + uv.w;
        o1.x = c1 * xb[j].x + uv.x; o1.y = c1 * xb[j].y + uv.y;
        o1.z = c1 * xb[j].z + uv.z; o1.w = c1 * xb[j].w + uv.w;
        *(float4*)(or0 + j * 256 + eoff) = o0;
        *(float4*)(or1 + j * 256 + eoff) = o1;
    }
}

extern "C" void kernel_launch(void* const* d_in, const int* in_sizes, int n_in,
                              void* d_out, int out_size, void* d_ws, size_t ws_size,
                              hipStream_t stream) {
    (void)in_sizes; (void)n_in; (void)d_ws; (void)ws_size; (void)out_size;
    const float* x = (const float*)d_in[0];
    const float* W = (const float*)d_in[1];
    const float* b = (const float*)d_in[2];
    float* out = (float*)d_out;
    cross_net_kernel<<<dim3(BLOCKS), dim3(THREADS), 0, stream>>>(x, W, b, out);
}

// Round 3
// 242.845 us; speedup vs baseline: 1.2692x; 1.2692x over previous
//
#include <hip/hip_runtime.h>

#define B_ROWS   16384
#define D_DIM    2048
#define L_LAYERS 6
#define THREADS  512                      // 8 waves/block
#define BLOCKS   1024                     // 8192 waves, 2 rows per wave
#define WPB      (THREADS / 64)
#define ROWS_PER_WAVE 2

// Exact algebra: x_l = c_l*x0 + u_l, u_l = sum_{i<l} b_i,
//   c_{l+1} = c_l*(1 + x0.W_l) + u_l.W_l.
// Whole net = 6 dots/row + scalar recurrence + out = c*x0 + U.
//
// One wave owns a row-pair end-to-end: zero barriers in the row phase,
// in-wave butterfly reduction, W/U staged in LDS once per block.
//
// NOTE on launch_bounds: (512,4) in R2 forced a 64-VGPR cap -> the 64-reg
// x prefetch spilled to scratch (HBM): WRITE_SIZE 131MB->364MB, 1.7x slower.
// Default cap (256) here; kernel needs ~110 VGPRs -> 16 waves/CU, same as
// the LDS limit (57KB -> 2 blocks/CU). No spill.
__global__ __launch_bounds__(THREADS) void cross_net_kernel(
    const float* __restrict__ x,
    const float* __restrict__ W,
    const float* __restrict__ b,
    float* __restrict__ out)
{
    __shared__ float Wl[L_LAYERS][D_DIM];   // 48 KB
    __shared__ float Ul[D_DIM];             // 8 KB
    __shared__ float red[WPB][L_LAYERS];

    const int t    = threadIdx.x;
    const int lane = t & 63;
    const int wid  = t >> 6;

    // ---- setup: stage W, U = sum b_i, e[l] = (sum_{i<l} b_i).W_l ----
    {
        const int base = t * 4;             // 512 threads x 4 = 2048
        float4 prefix = make_float4(0.f, 0.f, 0.f, 0.f);
        float e_red[L_LAYERS];
        #pragma unroll
        for (int l = 0; l < L_LAYERS; ++l) {
            const float4 wv = *(const float4*)(W + l * D_DIM + base);
            const float4 bv = *(const float4*)(b + l * D_DIM + base);
            e_red[l] = prefix.x * wv.x + prefix.y * wv.y +
                       prefix.z * wv.z + prefix.w * wv.w;   // prefix BEFORE b_l
            prefix.x += bv.x; prefix.y += bv.y; prefix.z += bv.z; prefix.w += bv.w;
            *(float4*)&Wl[l][base] = wv;
        }
        *(float4*)&Ul[base] = prefix;
        #pragma unroll
        for (int l = 0; l < L_LAYERS; ++l) {
            float v = e_red[l];
            #pragma unroll
            for (int off = 32; off >= 1; off >>= 1) v += __shfl_xor(v, off, 64);
            if (lane == 0) red[wid][l] = v;
        }
    }
    __syncthreads();                        // the ONLY barrier

    float e[L_LAYERS];
    #pragma unroll
    for (int l = 0; l < L_LAYERS; ++l) {
        float s = 0.f;
        #pragma unroll
        for (int w = 0; w < WPB; ++w) s += red[w][l];
        e[l] = s;
    }

    // ---- row phase: barrier-free, one wave per row-pair ----
    const int gw   = blockIdx.x * WPB + wid;
    const int row0 = gw * ROWS_PER_WAVE;
    const float* xr0 = x + (size_t)row0 * D_DIM;
    const float* xr1 = xr0 + D_DIM;
    const int eoff = lane * 4;              // + j*256, j=0..7 covers 2048

    float4 xa[8], xb[8];
    #pragma unroll
    for (int j = 0; j < 8; ++j) xa[j] = *(const float4*)(xr0 + j * 256 + eoff);
    #pragma unroll
    for (int j = 0; j < 8; ++j) xb[j] = *(const float4*)(xr1 + j * 256 + eoff);

    float p0[L_LAYERS], p1[L_LAYERS];
    #pragma unroll
    for (int l = 0; l < L_LAYERS; ++l) {
        float a0 = 0.f, a1 = 0.f;
        #pragma unroll
        for (int j = 0; j < 8; ++j) {
            const float4 wv = *(const float4*)&Wl[l][j * 256 + eoff];
            a0 += xa[j].x * wv.x + xa[j].y * wv.y + xa[j].z * wv.z + xa[j].w * wv.w;
            a1 += xb[j].x * wv.x + xb[j].y * wv.y + xb[j].z * wv.z + xb[j].w * wv.w;
        }
        p0[l] = a0; p1[l] = a1;
    }

    #pragma unroll
    for (int off = 32; off >= 1; off >>= 1) {
        #pragma unroll
        for (int l = 0; l < L_LAYERS; ++l) {
            p0[l] += __shfl_xor(p0[l], off, 64);
            p1[l] += __shfl_xor(p1[l], off, 64);
        }
    }

    float c0 = 1.f, c1 = 1.f;
    #pragma unroll
    for (int l = 0; l < L_LAYERS; ++l) {
        c0 = c0 * (1.f + p0[l]) + e[l];
        c1 = c1 * (1.f + p1[l]) + e[l];
    }

    float* or0 = out + (size_t)row0 * D_DIM;
    float* or1 = or0 + D_DIM;
    #pragma unroll
    for (int j = 0; j < 8; ++j) {
        const float4 uv = *(const float4*)&Ul[j * 256 + eoff];
        float4 o0, o1;
        o0.x = c0 * xa[j].x + uv.x; o0.y = c0 * xa[j].y + uv.y;
        o0.z = c0 * xa[j].z + uv.z; o0.w = c0 * xa[j].w + uv.w;
        o1.x = c1 * xb[j].x + uv.x; o1.y = c1 * xb[j].y + uv.y;
        o1.z = c1 * xb[j].z + uv.z; o1.w = c1 * xb[j].w + uv.w;
        *(float4*)(or0 + j * 256 + eoff) = o0;
        *(float4*)(or1 + j * 256 + eoff) = o1;
    }
}

extern "C" void kernel_launch(void* const* d_in, const int* in_sizes, int n_in,
                              void* d_out, int out_size, void* d_ws, size_t ws_size,
                              hipStream_t stream) {
    (void)in_sizes; (void)n_in; (void)d_ws; (void)ws_size; (void)out_size;
    const float* x = (const float*)d_in[0];
    const float* W = (const float*)d_in[1];
    const float* b = (const float*)d_in[2];
    float* out = (float*)d_out;
    cross_net_kernel<<<dim3(BLOCKS), dim3(THREADS), 0, stream>>>(x, W, b, out);
}